// Round 12
// baseline (302.704 us; speedup 1.0000x reference)
//
#include <hip/hip_runtime.h>

// DiffeomorphicTransform: flow = velocity/2^7; 7x { grid = sample_grid + flow*rf;
// flow = flow + trilerp(flow, grid) }  (border clamp, align_corners=True)
//
// R12 = R10 (channel-interleaved [N][3] intermediates, z-slab XCD swizzle,
// analytic identity grid, deferred exact /2^7) with the repack pass FUSED into
// step 1: step 1 reads planar velocity directly (displacement <= ~0.2 voxel at
// step 1, so planar pair-gathers are near-coalesced; line fan-out only matters
// at late steps, which stay interleaved). 7 dispatches instead of 8.
// R11's cooperative single-dispatch was rejected at launch (VGPR >64 broke
// 8-blocks/CU residency) — reverted per plan.

constexpr int D = 128, H = 160, W = 128;
constexpr int N = D * H * W;             // 2,621,440 voxels
constexpr int VOX_BLOCKS = N / 256;      // 10240 blocks
constexpr int NUM_XCD = 8;
constexpr int CHUNKS_PER_XCD = VOX_BLOCKS / NUM_XCD;   // 1280

// 4-byte-aligned float pair (x-adjacent corners, planar path)
struct __attribute__((packed)) fpair { float lo, hi; };

template <bool PLANAR_IN, bool PLANAR_OUT>
__global__ __launch_bounds__(256)
void diffeo_step(const void* __restrict__ src_raw,  // [N][3] or planar [3][N]
                 const float* __restrict__ rf_p,    // scalar range_flow
                 void* __restrict__ dst_raw,        // [N][3] or planar [3][N]
                 float scale)                       // 1/128 on step 1, else 1.0
{
    // z-slab XCD swizzle (R6-validated): XCD = blockIdx%8 owns a contiguous
    // slab walked sequentially (moving L2 window).
    const int b   = blockIdx.x;              // 0..10239
    const int xcd = b & (NUM_XCD - 1);
    const int k   = b >> 3;                  // 0..1279
    const int vb  = xcd * CHUNKS_PER_XCD + k;
    const int i   = vb * 256 + threadIdx.x;  // voxel id [0,N)

    const float rf = rf_p[0];

    // voxel coords (W=128 pow2)
    const int x = i & (W - 1);
    const int r = i >> 7;                    // z*H + y
    const int y = r % H;
    const int z = r / H;

    float3 f;
    if (PLANAR_IN) {
        const float* __restrict__ sp = (const float*)src_raw;
        f = make_float3(sp[i] * scale, sp[i + N] * scale, sp[i + 2 * N] * scale);
    } else {
        f = ((const float3*)src_raw)[i];
    }

    // analytic identity grid: unnormalized coord = x + flow*rf*0.5*(dim-1)
    const float ix = fminf(fmaxf((float)x + f.x * (rf * 0.5f * (float)(W - 1)), 0.0f), (float)(W - 1));
    const float iy = fminf(fmaxf((float)y + f.y * (rf * 0.5f * (float)(H - 1)), 0.0f), (float)(H - 1));
    const float iz = fminf(fmaxf((float)z + f.z * (rf * 0.5f * (float)(D - 1)), 0.0f), (float)(D - 1));

    const float x0f = floorf(ix), y0f = floorf(iy), z0f = floorf(iz);
    const float wx = ix - x0f, wy = iy - y0f, wz = iz - z0f;
    const int x0 = (int)x0f, y0 = (int)y0f, z0 = (int)z0f;
    const int y1 = min(y0 + 1, H - 1);
    const int z1 = min(z0 + 1, D - 1);

    // corner-pair base: x0==W-1 implies wx==0 (x1==x0) -> hi select is exact
    const int xb = min(x0, W - 2);
    const bool hix = (x0 == W - 1);

    int ofs[4];
    ofs[0] = (z0 * H + y0) * W + xb;
    ofs[1] = (z0 * H + y1) * W + xb;
    ofs[2] = (z1 * H + y0) * W + xb;
    ofs[3] = (z1 * H + y1) * W + xb;

    float3 p0[4], p1[4];
    if (PLANAR_IN) {
        const float* __restrict__ sp = (const float*)src_raw;
#pragma unroll
        for (int q = 0; q < 4; ++q) {
            const fpair ax = *(const fpair*)(sp + ofs[q]);
            const fpair ay = *(const fpair*)(sp + N + ofs[q]);
            const fpair az = *(const fpair*)(sp + 2 * N + ofs[q]);
            p0[q] = make_float3(ax.lo, ay.lo, az.lo);
            p1[q] = make_float3(ax.hi, ay.hi, az.hi);
        }
    } else {
        const float3* __restrict__ s3 = (const float3*)src_raw;
#pragma unroll
        for (int q = 0; q < 4; ++q) {
            p0[q] = s3[ofs[q]];
            p1[q] = s3[ofs[q] + 1];
        }
    }
    if (hix) {
#pragma unroll
        for (int q = 0; q < 4; ++q) p0[q] = p1[q];   // wx==0 here, exact
    }

    const float omx = 1.0f - wx, omy = 1.0f - wy, omz = 1.0f - wz;
    const float w00 = omz * omy, w01 = omz * wy, w10 = wz * omy, w11 = wz * wy;

    const float vx = w00 * (omx * p0[0].x + wx * p1[0].x)
                   + w01 * (omx * p0[1].x + wx * p1[1].x)
                   + w10 * (omx * p0[2].x + wx * p1[2].x)
                   + w11 * (omx * p0[3].x + wx * p1[3].x);
    const float vy = w00 * (omx * p0[0].y + wx * p1[0].y)
                   + w01 * (omx * p0[1].y + wx * p1[1].y)
                   + w10 * (omx * p0[2].y + wx * p1[2].y)
                   + w11 * (omx * p0[3].y + wx * p1[3].y);
    const float vz = w00 * (omx * p0[0].z + wx * p1[0].z)
                   + w01 * (omx * p0[1].z + wx * p1[1].z)
                   + w10 * (omx * p0[2].z + wx * p1[2].z)
                   + w11 * (omx * p0[3].z + wx * p1[3].z);

    // deferred scale on gathered values (trilerp is linear)
    const float o0 = f.x + vx * scale;
    const float o1 = f.y + vy * scale;
    const float o2 = f.z + vz * scale;

    if (PLANAR_OUT) {
        float* __restrict__ dp = (float*)dst_raw;
        dp[i] = o0; dp[i + N] = o1; dp[i + 2 * N] = o2;
    } else {
        ((float3*)dst_raw)[i] = make_float3(o0, o1, o2);
    }
}

extern "C" void kernel_launch(void* const* d_in, const int* in_sizes, int n_in,
                              void* d_out, int out_size, void* d_ws, size_t ws_size,
                              hipStream_t stream)
{
    const float* vel = (const float*)d_in[0];   // [1,3,128,160,128] planar
    const float* rf  = (const float*)d_in[2];   // scalar range_flow
    void* out3 = d_out;                         // d_out doubles as interleaved scratch
    void* ws3  = d_ws;                          // 31.5 MB interleaved buffer

    const dim3 blk(256);
    const dim3 grd(VOX_BLOCKS);                 // 10240 blocks

    // s1: planar velocity -> interleaved out3, repack + exact /2^7 fused
    diffeo_step<true,  false><<<grd, blk, 0, stream>>>(vel,  rf, out3, 1.0f / 128.0f);
    // s2..s6: interleaved ping-pong
    diffeo_step<false, false><<<grd, blk, 0, stream>>>(out3, rf, ws3,  1.0f);  // s2
    diffeo_step<false, false><<<grd, blk, 0, stream>>>(ws3,  rf, out3, 1.0f);  // s3
    diffeo_step<false, false><<<grd, blk, 0, stream>>>(out3, rf, ws3,  1.0f);  // s4
    diffeo_step<false, false><<<grd, blk, 0, stream>>>(ws3,  rf, out3, 1.0f);  // s5
    diffeo_step<false, false><<<grd, blk, 0, stream>>>(out3, rf, ws3,  1.0f);  // s6
    // s7: interleaved ws3 -> PLANAR d_out (reads only ws3; full overwrite)
    diffeo_step<false, true ><<<grd, blk, 0, stream>>>(ws3,  rf, d_out, 1.0f); // s7
}